// Round 9
// baseline (185.934 us; speedup 1.0000x reference)
//
#include <hip/hip_runtime.h>
#include <hip/hip_bf16.h>

typedef short short8 __attribute__((ext_vector_type(8)));
typedef float f32x4  __attribute__((ext_vector_type(4)));
typedef unsigned short us4 __attribute__((ext_vector_type(4)));

#define N_SEQ 8192
#define D_CH  512

constexpr int XSLOTS  = 1280;              // x ring slots (rows)
constexpr int XLDS_B  = XSLOTS * 8;        // 10240 B
constexpr int TSTRIDE = 528;               // 256 slots + 16B: bank base 4r, all 8 distinct
constexpr int TLDS_B  = 8 * TSTRIDE;       // 4224 B
constexpr int ALL_LDS = XLDS_B + TLDS_B;   // 14464 B -> 11 blocks/CU

__device__ __forceinline__ unsigned short f32_to_bf16_bits(float f) {
    union { float f; unsigned int u; } v; v.f = f;
    unsigned int u = v.u;
    unsigned int r = u + 0x7FFFu + ((u >> 16) & 1u);   // RNE
    return (unsigned short)(r >> 16);
}
__device__ __forceinline__ float bf16_to_f32(unsigned short u) {
  union { unsigned int u; float f; } v; v.u = ((unsigned int)u) << 16; return v.f;
}
// gelu tanh-approx: y = v * (1 - 1/(exp2(K1*v + K2*v^3) + 1))
__device__ __forceinline__ float gelu_f(float v) {
  float w = v * (2.3022031f + 0.10294296f * v * v);
  float e = __builtin_amdgcn_exp2f(w);
  float r = __builtin_amdgcn_rcpf(e + 1.0f);
  return v - v * r;
}

// ---------------- pre-pass: transpose + cast to bf16 ----------------
__global__ __launch_bounds__(256) void transpose_cast_kernel(
    const float* __restrict__ x, const float* __restrict__ t,
    unsigned short* __restrict__ xT, unsigned short* __restrict__ tT) {
  __shared__ float tile[64][65];
  int blk = blockIdx.x;
  int bat = blk >> 10;
  int rem = blk & 1023;
  int i0 = (rem >> 3) << 6;
  int d0 = (rem & 7) << 6;
  const float* src; unsigned short* dst;
  if (bat < 4) { src = x + (size_t)bat * N_SEQ * D_CH; dst = xT + (size_t)bat * D_CH * N_SEQ; }
  else         { src = t;                              dst = tT; }
  int tx = threadIdx.x & 63, ty = threadIdx.x >> 6;
  #pragma unroll
  for (int r = ty; r < 64; r += 4)
    tile[r][tx] = src[(size_t)(i0 + r) * D_CH + (d0 + tx)];
  __syncthreads();
  #pragma unroll
  for (int r = ty; r < 64; r += 4)
    dst[(size_t)(d0 + r) * N_SEQ + (i0 + tx)] = f32_to_bf16_bits(tile[tx][r]);
}

// ---------------- output transpose: (d,b,i) bf16 -> (b,i,d) f32 ----------------
__global__ __launch_bounds__(256) void transpose_out_kernel(
    const unsigned short* __restrict__ src, float* __restrict__ dst) {
  __shared__ float tile[64][65];
  int blk = blockIdx.x;
  int b   = blk >> 10;
  int rem = blk & 1023;
  int d0 = (rem & 7) << 6;
  int i0 = (rem >> 3) << 6;
  int tx = threadIdx.x & 63, ty = threadIdx.x >> 6;
  #pragma unroll
  for (int r = ty; r < 64; r += 4)
    tile[r][tx] = bf16_to_f32(src[((size_t)(d0 + r) * 4 + b) * N_SEQ + i0 + tx]);
  __syncthreads();
  #pragma unroll
  for (int r = ty; r < 64; r += 4)
    dst[((size_t)b * N_SEQ + i0 + r) * D_CH + d0 + tx] = tile[tx][r];
}

// ---------------- main kernel ----------------
// 1 wave/block; grid 4096: blk = sblk*512 + d, strip = 7-sblk, XCD = d%8.
// acc[2][8]: 2 col-groups (512 rows) x 8 lag sub-shifts. Per iter (32 lags):
// 2 fresh af (k=0,1; k>=2 rotated) + 2 bf reads feed 16 MFMAs.
// x ring: byte(s,b) = s*8 + b*16, physically XOR-swizzled:
//   phys = lin ^ ((lin>>10&1)<<6) ^ ((lin>>11&1)<<5)   [bits 10,11 const per 256B region]
// t ring: 8 reversed copies, copy r slot u = (r - idx)&255 at byte r*528 + u*2.
template<int DMAJOR>
__global__ __launch_bounds__(64, 3) void tno_conv_kernel(
    const unsigned short* __restrict__ xT, const unsigned short* __restrict__ tT,
    unsigned short* __restrict__ owsp, float* __restrict__ outp) {
  __shared__ __align__(16) char lds[ALL_LDS];
  const int lane = threadIdx.x & 63;
  const int blk  = blockIdx.x;
  const int d    = blk & 511;
  const int strip = 7 - (blk >> 9);
  const int base  = strip << 10;
  const int l_hi  = base + 896;

  // MFMA lane constants
  const int m      = lane & 15;
  const int kb     = (lane >> 4) << 3;
  const int bcol   = m & 3;
  const int sl     = m >> 2;
  const int rA     = m & 7;
  const int aConst = kb - (m & 8);
  char* ldsX = lds;
  char* ldsT = lds + XLDS_B;
  const char* tb = ldsT + rA * TSTRIDE;
  // t staging lane mapping
  const int stJ  = lane & 31;
  const int stR0 = (lane >> 5) << 2;
  const unsigned short* tTd = tT + ((size_t)d << 13);
  // x staging lane mapping (DMA dst byte = 4*lane within each 256B region)
  const int sb   = (lane >> 2) & 3;
  const int uLin = (lane & 3) | ((lane >> 4) << 2);
  const unsigned short* xlaneB = xT + (((size_t)sb * D_CH + d) << 13) + (uLin << 1);
  // swizzle source adjustments (elements): bit10 flips row bit3, bit11 flips batch bit1
  const int rowAdj = ((lane >> 4) & 1) ? -8 : 8;
  const int batAdj = (sb & 2) ? -8388608 : 8388608;   // 2 * 512 * 8192 elements

  typedef __attribute__((address_space(3))) unsigned int lds_u32;
  typedef const __attribute__((address_space(1))) unsigned int glb_u32;

  f32x4 acc[2][8];
  #pragma unroll
  for (int g = 0; g < 2; ++g)
    #pragma unroll
    for (int k = 0; k < 8; ++k)
      acc[g][k] = (f32x4){0.f, 0.f, 0.f, 0.f};

  // t prologue loads: values [l_hi-32, l_hi+127]  (max idx = base+1023 <= 8191)
  unsigned short tp[5];
  #pragma unroll
  for (int q = 0; q < 5; ++q)
    tp[q] = tTd[l_hi + 96 - (q << 5) + stJ];
  asm volatile("" ::: "memory");

  // x prologue: zero rows [-384,-1] (slots 896..1279), DMA rows [0,255]
  {
    f32x4 z = (f32x4){0.f, 0.f, 0.f, 0.f};
    #pragma unroll
    for (int j = 0; j < 3; ++j)
      *(f32x4*)(ldsX + 7168 + (j << 10) + (lane << 4)) = z;
    #pragma unroll
    for (int j = 0; j < 8; ++j)
      __builtin_amdgcn_global_load_lds(
          (glb_u32*)(const void*)(xlaneB + (j << 5) + ((j & 4) ? rowAdj : 0)),
          (lds_u32*)(void*)(ldsX + (j << 8)), 4, 0, 0);
  }
  asm volatile("" ::: "memory");

  // t prologue ring writes
  #pragma unroll
  for (int c = 0; c < 4; ++c) {
    int r = stR0 + c;
    char* cw = ldsT + r * TSTRIDE;
    #pragma unroll
    for (int q = 0; q < 5; ++q) {
      int idx = l_hi + 96 - (q << 5) + stJ;
      *(unsigned short*)(cw + (((r - idx) & 255) << 1)) = tp[q];
    }
  }

  // t register pipe prefill (idx >= 609 for all strips)
  unsigned short tv[8];
  #pragma unroll
  for (int u = 0; u < 8; ++u)
    tv[u] = tTd[l_hi - 63 - (u << 5) + stJ];

  asm volatile("s_waitcnt vmcnt(0)" ::: "memory");

  // ---- loop state (all incremental) ----
  int aC = ((aConst - l_hi) & 255) << 1;   // k=0 byte offset at current l
  short8 af0, af1;
  short8 af2 = *(const short8*)(tb + ((aC - 64)  & 511));
  short8 af3 = *(const short8*)(tb + ((aC - 96)  & 511));
  short8 af4 = *(const short8*)(tb + ((aC - 128) & 511));
  short8 af5 = *(const short8*)(tb + ((aC - 160) & 511));
  short8 af6 = *(const short8*)(tb + ((aC - 192) & 511));
  short8 af7 = *(const short8*)(tb + ((aC - 224) & 511));
  int xo[2];
  #pragma unroll
  for (int g = 0; g < 2; ++g) {
    int row = (base - l_hi) + (g << 9) + (sl << 7) + kb;   // in [-896, 24]
    if (row < 0) row += XSLOTS;
    xo[g] = (row << 3) + (bcol << 4);
  }
  int twb[4];
  #pragma unroll
  for (int c = 0; c < 4; ++c)
    twb[c] = (((stR0 + c) - (l_hi - 63 + stJ)) & 255) << 1;
  int tgi = l_hi - 319 + stJ;                // next t load idx (8 iters ahead)
  const unsigned short* xsp = xlaneB + 256;  // next DMA: rows [256,287]
  int wb = 2048;

#define CONV_ITER(GMIN, U)                                                       \
  {                                                                              \
    asm volatile("s_waitcnt vmcnt(14)" ::: "memory");                            \
    af0 = *(const short8*)(tb + aC);                                             \
    af1 = *(const short8*)(tb + ((aC - 32) & 511));                              \
    { const unsigned short* xs = xsp + ((wb & 1024) ? rowAdj : 0)                \
                                     + ((wb & 2048) ? batAdj : 0);               \
      __builtin_amdgcn_global_load_lds((glb_u32*)(const void*)xs,                \
          (lds_u32*)(void*)(ldsX + wb), 4, 0, 0); }                              \
    __builtin_amdgcn_s_setprio(1);                                               \
    _Pragma("unroll")                                                            \
    for (int g = 0; g < 2; ++g) {                                                \
      if (g >= (GMIN)) {                                                         \
        int xsw = xo[g] ^ ((xo[g] & 1024) >> 4) ^ ((xo[g] & 2048) >> 6);         \
        short8 bf = *(const short8*)(ldsX + xsw);                                \
        acc[g][2] = __builtin_amdgcn_mfma_f32_16x16x32_bf16(af2, bf, acc[g][2], 0, 0, 0); \
        acc[g][3] = __builtin_amdgcn_mfma_f32_16x16x32_bf16(af3, bf, acc[g][3], 0, 0, 0); \
        acc[g][4] = __builtin_amdgcn_mfma_f32_16x16x32_bf16(af4, bf, acc[g][4], 0, 0, 0); \
        acc[g][5] = __builtin_amdgcn_mfma_f32_16x16x32_bf16(af5, bf, acc[g][5], 0, 0, 0); \
        acc[g][6] = __builtin_amdgcn_mfma_f32_16x16x32_bf16(af6, bf, acc[g][6], 0, 0, 0); \
        acc[g][7] = __builtin_amdgcn_mfma_f32_16x16x32_bf16(af7, bf, acc[g][7], 0, 0, 0); \
        acc[g][0] = __builtin_amdgcn_mfma_f32_16x16x32_bf16(af0, bf, acc[g][0], 0, 0, 0); \
        acc[g][1] = __builtin_amdgcn_mfma_f32_16x16x32_bf16(af1, bf, acc[g][1], 0, 0, 0); \
      }                                                                          \
      xo[g] += 256; if (xo[g] >= XLDS_B) xo[g] -= XLDS_B;                        \
    }                                                                            \
    __builtin_amdgcn_s_setprio(0);                                               \
    { unsigned short tvs = tv[U];                                                \
      _Pragma("unroll")                                                          \
      for (int c = 0; c < 4; ++c) {                                              \
        *(unsigned short*)(ldsT + (stR0 + c) * TSTRIDE + twb[c]) = tvs;          \
        twb[c] = (twb[c] + 64) & 511;                                            \
      }                                                                          \
    }                                                                            \
    { int ti = (tgi < 0) ? 0 : tgi;                                              \
      unsigned short v = tTd[ti];          /* always issued: stable vmcnt */     \
      tv[U] = (tgi < 0) ? (unsigned short)0 : v;                                 \
      tgi -= 32; }                                                               \
    af7 = af5; af6 = af4; af5 = af3; af4 = af2; af3 = af1; af2 = af0;            \
    aC = (aC + 64) & 511;                                                        \
    xsp += 32;                                                                   \
    wb += 256; if (wb >= XLDS_B) wb -= XLDS_B;                                   \
  }

#define PH8(GMIN)                                                                \
    { _Pragma("unroll")                                                          \
      for (int u = 0; u < 8; ++u) CONV_ITER(GMIN, u) }

  PH8(1)                                  // l = base+896 .. base+672 (group 1 only)
  PH8(1)                                  // l = base+640 .. base+416
  const int n0 = (strip << 2) + 2;        // (32*strip+16)/8 blocks of 8
  #pragma unroll 1
  for (int c8 = 0; c8 < n0; ++c8)
    PH8(0)                                // l = base+384 .. -96
#undef PH8
#undef CONV_ITER

  // drain in-flight DMA so nothing lands in a successor block's LDS
  asm volatile("s_waitcnt vmcnt(0)" ::: "memory");

  // ---- epilogue: gelu + store ----
  if (DMAJOR) {
    unsigned short* op = owsp + ((((size_t)d << 2) + bcol) << 13) + base
                       + (sl << 7) + ((lane >> 4) << 2);
    #pragma unroll
    for (int g = 0; g < 2; ++g)
      #pragma unroll
      for (int k = 0; k < 8; ++k) {
        us4 w;
        #pragma unroll
        for (int r = 0; r < 4; ++r)
          w[r] = f32_to_bf16_bits(gelu_f(acc[g][k][r]));
        *(us4*)(op + (g << 9) + (k << 4)) = w;
      }
  } else {
    #pragma unroll
    for (int g = 0; g < 2; ++g)
      #pragma unroll
      for (int k = 0; k < 8; ++k)
        #pragma unroll
        for (int r = 0; r < 4; ++r) {
          int i = base + (g << 9) + (sl << 7) + (k << 4) + ((lane >> 4) << 2) + r;
          outp[(((size_t)bcol << 13) + (size_t)i) * D_CH + d] = gelu_f(acc[g][k][r]);
        }
  }
}

extern "C" void kernel_launch(void* const* d_in, const int* in_sizes, int n_in,
                              void* d_out, int out_size, void* d_ws, size_t ws_size,
                              hipStream_t stream) {
  const float* x = (const float*)d_in[0];
  const float* t = (const float*)d_in[1];
  float* out = (float*)d_out;

  const size_t xT_elems = (size_t)4 * D_CH * N_SEQ;       // bf16
  const size_t tT_elems = (size_t)D_CH * N_SEQ;           // bf16
  unsigned short* xT  = (unsigned short*)d_ws;
  unsigned short* tT  = xT + xT_elems;
  unsigned short* ows = tT + tT_elems;                    // bf16 intermediate
  const size_t need = (xT_elems + tT_elems + xT_elems) * 2;   // ~75.5 MB
  const bool dmaj = (ws_size >= need);

  hipLaunchKernelGGL(transpose_cast_kernel, dim3(5 * 1024), dim3(256), 0, stream,
                     x, t, xT, tT);
  if (dmaj) {
    hipLaunchKernelGGL((tno_conv_kernel<1>), dim3(4096), dim3(64), 0, stream,
                       xT, tT, ows, out);
    hipLaunchKernelGGL(transpose_out_kernel, dim3(4096), dim3(256), 0, stream,
                       ows, out);
  } else {
    hipLaunchKernelGGL((tno_conv_kernel<0>), dim3(4096), dim3(64), 0, stream,
                       xT, tT, ows, out);
  }
}

// Round 10
// 170.523 us; speedup vs baseline: 1.0904x; 1.0904x over previous
//
#include <hip/hip_runtime.h>
#include <hip/hip_bf16.h>

typedef short short8 __attribute__((ext_vector_type(8)));
typedef float f32x4  __attribute__((ext_vector_type(4)));
typedef unsigned short us4 __attribute__((ext_vector_type(4)));

#define N_SEQ 8192
#define D_CH  512

constexpr int XSLOTS  = 1536;              // x ring: 1024-row frame + 16-iter margin
constexpr int XLDS_B  = XSLOTS * 8;        // 12288 B; byte(s,b) = s*8 + b*16 (s mult of 8)
constexpr int TSTRIDE = 272;               // per reversed-t copy (R7 proven)
constexpr int TLDS_B  = 8 * TSTRIDE;       // 2176 B
constexpr int ALL_LDS = XLDS_B + TLDS_B;   // 14464 B -> 11 blocks/CU

__device__ __forceinline__ unsigned short f32_to_bf16_bits(float f) {
    union { float f; unsigned int u; } v; v.f = f;
    unsigned int u = v.u;
    unsigned int r = u + 0x7FFFu + ((u >> 16) & 1u);   // RNE
    return (unsigned short)(r >> 16);
}
__device__ __forceinline__ float bf16_to_f32(unsigned short u) {
  union { unsigned int u; float f; } v; v.u = ((unsigned int)u) << 16; return v.f;
}
// gelu tanh-approx: y = v * (1 - 1/(exp2(K1*v + K2*v^3) + 1))
__device__ __forceinline__ float gelu_f(float v) {
  float w = v * (2.3022031f + 0.10294296f * v * v);
  float e = __builtin_amdgcn_exp2f(w);
  float r = __builtin_amdgcn_rcpf(e + 1.0f);
  return v - v * r;
}

// ---------------- pre-pass: transpose + cast to bf16 ----------------
__global__ __launch_bounds__(256) void transpose_cast_kernel(
    const float* __restrict__ x, const float* __restrict__ t,
    unsigned short* __restrict__ xT, unsigned short* __restrict__ tT) {
  __shared__ float tile[64][65];
  int blk = blockIdx.x;
  int bat = blk >> 10;
  int rem = blk & 1023;
  int i0 = (rem >> 3) << 6;
  int d0 = (rem & 7) << 6;
  const float* src; unsigned short* dst;
  if (bat < 4) { src = x + (size_t)bat * N_SEQ * D_CH; dst = xT + (size_t)bat * D_CH * N_SEQ; }
  else         { src = t;                              dst = tT; }
  int tx = threadIdx.x & 63, ty = threadIdx.x >> 6;
  #pragma unroll
  for (int r = ty; r < 64; r += 4)
    tile[r][tx] = src[(size_t)(i0 + r) * D_CH + (d0 + tx)];
  __syncthreads();
  #pragma unroll
  for (int r = ty; r < 64; r += 4)
    dst[(size_t)(d0 + r) * N_SEQ + (i0 + tx)] = f32_to_bf16_bits(tile[tx][r]);
}

// ---------------- output transpose: (d,b,i) bf16 -> (b,i,d) f32 ----------------
__global__ __launch_bounds__(256) void transpose_out_kernel(
    const unsigned short* __restrict__ src, float* __restrict__ dst) {
  __shared__ float tile[64][65];
  int blk = blockIdx.x;
  int b   = blk >> 10;
  int rem = blk & 1023;
  int d0 = (rem & 7) << 6;
  int i0 = (rem >> 3) << 6;
  int tx = threadIdx.x & 63, ty = threadIdx.x >> 6;
  #pragma unroll
  for (int r = ty; r < 64; r += 4)
    tile[r][tx] = bf16_to_f32(src[((size_t)(d0 + r) * 4 + b) * N_SEQ + i0 + tx]);
  __syncthreads();
  #pragma unroll
  for (int r = ty; r < 64; r += 4)
    dst[((size_t)b * N_SEQ + i0 + r) * D_CH + d0 + tx] = tile[tx][r];
}

// ---------------- main kernel ----------------
// R7 structure (4g x 4k acc, proven 129us) + 16-iter-deep DMA pipeline.
// 1 wave/block; grid 4096: blk = sblk*512 + d, strip = 7-sblk, XCD = d%8.
// Lag-blocks l DESCEND from base+960 to -32 (32*strip+32 iters).
// x ring 1536 slots = read frame (1024 rows) + 15.25-iter staged-ahead margin;
// per-iter counted vmcnt(30) (2 vmem ops/iter, 32 in flight).
// t values flow through a 16-deep register pipe tv[16] (static idx via unroll).
template<int DMAJOR>
__global__ __launch_bounds__(64, 3) void tno_conv_kernel(
    const unsigned short* __restrict__ xT, const unsigned short* __restrict__ tT,
    unsigned short* __restrict__ owsp, float* __restrict__ outp) {
  __shared__ __align__(16) char lds[ALL_LDS];
  const int lane = threadIdx.x & 63;
  const int blk  = blockIdx.x;
  const int d    = blk & 511;
  const int strip = 7 - (blk >> 9);
  const int base  = strip << 10;
  const int l_hi  = base + 960;

  // MFMA lane constants
  const int m      = lane & 15;
  const int kb     = (lane >> 4) << 3;
  const int bcol   = m & 3;
  const int sl     = m >> 2;
  const int rA     = m & 7;
  const int aConst = kb - (m & 8);
  char* ldsX = lds;
  char* ldsT = lds + XLDS_B;
  const char* tb = ldsT + rA * TSTRIDE;
  // t staging lane mapping
  const int stJ  = lane & 31;
  const int stR0 = (lane >> 5) << 2;
  const unsigned short* tTd = tT + ((size_t)d << 13);
  // x staging lane mapping (DMA dst byte = 4*lane within each 256B region)
  const int uLin = (lane & 3) | ((lane >> 4) << 2);
  const int sb   = (lane >> 2) & 3;
  const unsigned short* xlaneB = xT + (((size_t)sb * D_CH + d) << 13) + (uLin << 1);

  typedef __attribute__((address_space(3))) unsigned int lds_u32;
  typedef const __attribute__((address_space(1))) unsigned int glb_u32;

  f32x4 acc[4][4];
  #pragma unroll
  for (int g = 0; g < 4; ++g)
    #pragma unroll
    for (int k = 0; k < 4; ++k)
      acc[g][k] = (f32x4){0.f, 0.f, 0.f, 0.f};

  // t prologue loads first (their consumption never drains the x queue)
  unsigned short tp0 = tTd[l_hi + 32 + stJ];   // values [l_hi+32, l_hi+63]
  unsigned short tp1 = tTd[l_hi + stJ];        // [l_hi, l_hi+31]
  unsigned short tp2 = tTd[l_hi - 32 + stJ];   // [l_hi-32, l_hi-1]
  asm volatile("" ::: "memory");

  // x prologue: zero rows [-960,-1] (slots 576..1535, bytes 4608..12287),
  // DMA rows [0,511] (16 issues)
  {
    f32x4 z = (f32x4){0.f, 0.f, 0.f, 0.f};
    #pragma unroll
    for (int j = 0; j < 7; ++j)
      *(f32x4*)(ldsX + 4608 + (j << 10) + (lane << 4)) = z;
    *(unsigned long long*)(ldsX + 11776 + (lane << 3)) = 0ull;
    #pragma unroll
    for (int j = 0; j < 16; ++j)
      __builtin_amdgcn_global_load_lds((glb_u32*)(const void*)(xlaneB + (j << 5)),
                                       (lds_u32*)(void*)(ldsX + (j << 8)), 4, 0, 0);
  }
  asm volatile("" ::: "memory");

  // t prologue writes (stage values [l_hi-32, l_hi+63] into all 8 copies)
  #pragma unroll
  for (int c = 0; c < 4; ++c) {
    int r = stR0 + c;
    char* cw = ldsT + r * TSTRIDE;
    *(unsigned short*)(cw + (((r - (l_hi + 32 + stJ)) & 127) << 1)) = tp0;
    *(unsigned short*)(cw + (((r - (l_hi      + stJ)) & 127) << 1)) = tp1;
    *(unsigned short*)(cw + (((r - (l_hi - 32 + stJ)) & 127) << 1)) = tp2;
  }

  // t register pipe prefill: tv[u] = value written at iter u (idx >= 417 always)
  unsigned short tv[16];
  #pragma unroll
  for (int u = 0; u < 16; ++u)
    tv[u] = tTd[l_hi - 63 - (u << 5) + stJ];

  // ---- loop state (all incremental) ----
  int aC = ((aConst - l_hi) & 127) << 1;                 // k=0 byte at current l
  short8 af2, af3;
  {
    // prime k=2,3 (t-ring writes visible via lgkmcnt; tp loads waited by compiler)
    af2 = *(const short8*)(tb + ((aC - 64) & 255));
    af3 = *(const short8*)(tb + ((aC - 96) & 255));
  }
  int xo[4];
  #pragma unroll
  for (int g = 0; g < 4; ++g) {
    int row = (base - l_hi) + (g << 8) + (sl << 6) + kb;   // in [-960, 24]
    if (row < 0) row += XSLOTS;
    xo[g] = (row << 3) + (bcol << 4);
  }
  int twb[4];
  #pragma unroll
  for (int c = 0; c < 4; ++c)
    twb[c] = (((stR0 + c) - (l_hi - 63 + stJ)) & 127) << 1;
  int tgi = l_hi - 575 + stJ;                  // next t load idx (16 iters ahead)
  const unsigned short* xsp = xlaneB + 512;    // next DMA: rows [512,543]
  int wb = 4096;

#define CONV_ITER(GMIN, U)                                                       \
  {                                                                              \
    asm volatile("s_waitcnt vmcnt(30)" ::: "memory");                            \
    short8 af0 = *(const short8*)(tb + aC);                                      \
    short8 af1 = *(const short8*)(tb + ((aC - 32) & 255));                       \
    __builtin_amdgcn_global_load_lds((glb_u32*)(const void*)xsp,                 \
        (lds_u32*)(void*)(ldsX + wb), 4, 0, 0);                                  \
    __builtin_amdgcn_s_setprio(1);                                               \
    _Pragma("unroll")                                                            \
    for (int g = 0; g < 4; ++g) {                                                \
      if (g >= (GMIN)) {                                                         \
        short8 bf = *(const short8*)(ldsX + xo[g]);                              \
        acc[g][0] = __builtin_amdgcn_mfma_f32_16x16x32_bf16(af0, bf, acc[g][0], 0, 0, 0); \
        acc[g][1] = __builtin_amdgcn_mfma_f32_16x16x32_bf16(af1, bf, acc[g][1], 0, 0, 0); \
        acc[g][2] = __builtin_amdgcn_mfma_f32_16x16x32_bf16(af2, bf, acc[g][2], 0, 0, 0); \
        acc[g][3] = __builtin_amdgcn_mfma_f32_16x16x32_bf16(af3, bf, acc[g][3], 0, 0, 0); \
      }                                                                          \
      xo[g] += 256; if (xo[g] >= XLDS_B) xo[g] -= XLDS_B;                        \
    }                                                                            \
    __builtin_amdgcn_s_setprio(0);                                               \
    { unsigned short tvs = tv[U];                                                \
      _Pragma("unroll")                                                          \
      for (int c = 0; c < 4; ++c) {                                              \
        *(unsigned short*)(ldsT + (stR0 + c) * TSTRIDE + twb[c]) = tvs;          \
        twb[c] = (twb[c] + 64) & 255;                                            \
      }                                                                          \
    }                                                                            \
    { int ti = (tgi < 0) ? 0 : tgi;                                              \
      unsigned short v = tTd[ti];          /* always issued: stable vmcnt */     \
      tv[U] = (tgi < 0) ? (unsigned short)0 : v;                                 \
      tgi -= 32; }                                                               \
    af2 = af0; af3 = af1;                                                        \
    aC = (aC + 64) & 255;                                                        \
    xsp += 32;                                                                   \
    wb += 256; if (wb >= XLDS_B) wb -= XLDS_B;                                   \
  }

#define PH8(GMIN, UB)                                                            \
    { _Pragma("unroll")                                                          \
      for (int u = 0; u < 8; ++u) CONV_ITER(GMIN, (UB) + u) }

  PH8(3, 0)                               // l = base+960 .. base+736
  PH8(2, 8)                               // l = base+704 .. base+480
  PH8(1, 0)                               // l = base+448 .. base+224
  #pragma unroll 1
  for (int i2 = 0; i2 < (strip << 1); ++i2) {   // 2s pairs of 8
    PH8(0, 8)
    PH8(0, 0)
  }
  PH8(0, 8)                               // final 8: total (4s+1) PH8(0)
#undef PH8
#undef CONV_ITER

  // drain in-flight DMA so nothing lands in a successor block's LDS
  asm volatile("s_waitcnt vmcnt(0)" ::: "memory");

  // ---- epilogue: gelu + store ----
  if (DMAJOR) {
    unsigned short* op = owsp + ((((size_t)d << 2) + bcol) << 13) + base
                       + (sl << 6) + ((lane >> 4) << 2);
    #pragma unroll
    for (int g = 0; g < 4; ++g)
      #pragma unroll
      for (int k = 0; k < 4; ++k) {
        us4 w;
        #pragma unroll
        for (int r = 0; r < 4; ++r)
          w[r] = f32_to_bf16_bits(gelu_f(acc[g][k][r]));
        *(us4*)(op + (g << 8) + (k << 4)) = w;
      }
  } else {
    #pragma unroll
    for (int g = 0; g < 4; ++g)
      #pragma unroll
      for (int k = 0; k < 4; ++k)
        #pragma unroll
        for (int r = 0; r < 4; ++r) {
          int i = base + (((g << 2) + sl) << 6) + (k << 4) + ((lane >> 4) << 2) + r;
          outp[(((size_t)bcol << 13) + (size_t)i) * D_CH + d] = gelu_f(acc[g][k][r]);
        }
  }
}

extern "C" void kernel_launch(void* const* d_in, const int* in_sizes, int n_in,
                              void* d_out, int out_size, void* d_ws, size_t ws_size,
                              hipStream_t stream) {
  const float* x = (const float*)d_in[0];
  const float* t = (const float*)d_in[1];
  float* out = (float*)d_out;

  const size_t xT_elems = (size_t)4 * D_CH * N_SEQ;       // bf16
  const size_t tT_elems = (size_t)D_CH * N_SEQ;           // bf16
  unsigned short* xT  = (unsigned short*)d_ws;
  unsigned short* tT  = xT + xT_elems;
  unsigned short* ows = tT + tT_elems;                    // bf16 intermediate
  const size_t need = (xT_elems + tT_elems + xT_elems) * 2;   // ~75.5 MB
  const bool dmaj = (ws_size >= need);

  hipLaunchKernelGGL(transpose_cast_kernel, dim3(5 * 1024), dim3(256), 0, stream,
                     x, t, xT, tT);
  if (dmaj) {
    hipLaunchKernelGGL((tno_conv_kernel<1>), dim3(4096), dim3(64), 0, stream,
                       xT, tT, ows, out);
    hipLaunchKernelGGL(transpose_out_kernel, dim3(4096), dim3(256), 0, stream,
                       ows, out);
  } else {
    hipLaunchKernelGGL((tno_conv_kernel<0>), dim3(4096), dim3(64), 0, stream,
                       xT, tT, ows, out);
  }
}